// Round 1
// baseline (1178.505 us; speedup 1.0000x reference)
//
#include <hip/hip_runtime.h>
#include <hip/hip_bf16.h>
#include <cstdint>

#define E_LOCAL 8
#define HIDDEN  2048
#define INTER   1408
#define MPE     1024      // tokens per expert (8192/8)
#define BK      64
#define LDP     72        // padded LDS row stride in bf16 elems (+8 => 2-way bank alias only)

typedef __attribute__((ext_vector_type(8))) __bf16 bf16x8;
typedef __attribute__((ext_vector_type(4))) float  f32x4;

// round-to-nearest-even f32 -> bf16 bits (inputs are finite; no NaN path needed)
__device__ __forceinline__ unsigned short f2b(float f) {
    unsigned int u = __float_as_uint(f);
    unsigned int r = (u + 0x7fffu + ((u >> 16) & 1u)) >> 16;
    return (unsigned short)r;
}

// ---------------- GEMM1: down_in[e,m,i] = silu(A@Wg^T) * (A@Wu^T), blocked dequant ----------------
__global__ __launch_bounds__(256, 2) void gemm1_kernel(
        const float* __restrict__ hidden,      // [E*MPE, HIDDEN]
        const float* __restrict__ w1,          // [E, 2*INTER, HIDDEN]
        const float* __restrict__ s1,          // [E, 22, 16]
        unsigned short* __restrict__ down_in)  // [E, MPE, INTER] bf16
{
    __shared__ unsigned short sA[128 * LDP];
    __shared__ unsigned short sG[128 * LDP];
    __shared__ unsigned short sU[128 * LDP];

    const int nx = blockIdx.x;   // 0..10  (INTER/128)
    const int my = blockIdx.y;   // 0..7   (MPE/128)
    const int e  = blockIdx.z;   // 0..7
    const int t  = threadIdx.x;
    const int lane = t & 63;
    const int wave = t >> 6;
    const int wm   = (wave >> 1) * 64;
    const int wn   = (wave & 1) * 64;
    const int l16  = lane & 15;
    const int quad = lane >> 4;

    const float* Abase = hidden + ((size_t)e * MPE + (size_t)my * 128) * HIDDEN;
    const float* Gbase = w1 + ((size_t)e * (2 * INTER) + (size_t)nx * 128) * HIDDEN;
    const float* Ubase = w1 + ((size_t)e * (2 * INTER) + INTER + (size_t)nx * 128) * HIDDEN;

    f32x4 accg[4][4], accu[4][4];
    #pragma unroll
    for (int i = 0; i < 4; ++i)
        #pragma unroll
        for (int j = 0; j < 4; ++j) {
            accg[i][j] = {0.f, 0.f, 0.f, 0.f};
            accu[i][j] = {0.f, 0.f, 0.f, 0.f};
        }

    for (int kt = 0; kt < HIDDEN / BK; ++kt) {
        const int k0 = kt * BK;
        const int kb = k0 >> 7;                       // 128-block index along K
        const float sg = s1[(e * 22 + nx) * 16 + kb];
        const float su = s1[(e * 22 + 11 + nx) * 16 + kb];

        __syncthreads();
        // stage A (128 x 64 f32 -> bf16)
        #pragma unroll
        for (int i = 0; i < 8; ++i) {
            int idx = i * 256 + t;
            int r = idx >> 4, c4 = idx & 15;
            float4 v = *(const float4*)(Abase + (size_t)r * HIDDEN + k0 + c4 * 4);
            ushort4 p = { f2b(v.x), f2b(v.y), f2b(v.z), f2b(v.w) };
            *(ushort4*)&sA[r * LDP + c4 * 4] = p;
        }
        // stage gate weights (dequant folded)
        #pragma unroll
        for (int i = 0; i < 8; ++i) {
            int idx = i * 256 + t;
            int r = idx >> 4, c4 = idx & 15;
            float4 v = *(const float4*)(Gbase + (size_t)r * HIDDEN + k0 + c4 * 4);
            ushort4 p = { f2b(v.x * sg), f2b(v.y * sg), f2b(v.z * sg), f2b(v.w * sg) };
            *(ushort4*)&sG[r * LDP + c4 * 4] = p;
        }
        // stage up weights (dequant folded)
        #pragma unroll
        for (int i = 0; i < 8; ++i) {
            int idx = i * 256 + t;
            int r = idx >> 4, c4 = idx & 15;
            float4 v = *(const float4*)(Ubase + (size_t)r * HIDDEN + k0 + c4 * 4);
            ushort4 p = { f2b(v.x * su), f2b(v.y * su), f2b(v.z * su), f2b(v.w * su) };
            *(ushort4*)&sU[r * LDP + c4 * 4] = p;
        }
        __syncthreads();

        #pragma unroll
        for (int kk = 0; kk < BK; kk += 32) {
            bf16x8 af[4], gf[4], uf[4];
            #pragma unroll
            for (int i = 0; i < 4; ++i) {
                af[i] = *(const bf16x8*)&sA[(wm + i * 16 + l16) * LDP + kk + quad * 8];
                gf[i] = *(const bf16x8*)&sG[(wn + i * 16 + l16) * LDP + kk + quad * 8];
                uf[i] = *(const bf16x8*)&sU[(wn + i * 16 + l16) * LDP + kk + quad * 8];
            }
            #pragma unroll
            for (int mi = 0; mi < 4; ++mi)
                #pragma unroll
                for (int ni = 0; ni < 4; ++ni) {
                    accg[mi][ni] = __builtin_amdgcn_mfma_f32_16x16x32_bf16(af[mi], gf[ni], accg[mi][ni], 0, 0, 0);
                    accu[mi][ni] = __builtin_amdgcn_mfma_f32_16x16x32_bf16(af[mi], uf[ni], accu[mi][ni], 0, 0, 0);
                }
        }
    }

    // epilogue: silu(gate)*up -> bf16 down_in
    unsigned short* Obase = down_in + ((size_t)e * MPE + (size_t)my * 128) * INTER + (size_t)nx * 128;
    #pragma unroll
    for (int mi = 0; mi < 4; ++mi)
        #pragma unroll
        for (int ni = 0; ni < 4; ++ni)
            #pragma unroll
            for (int r = 0; r < 4; ++r) {
                float g = accg[mi][ni][r];
                float u = accu[mi][ni][r];
                float d = g / (1.f + __expf(-g)) * u;
                int m = wm + mi * 16 + quad * 4 + r;
                int c = wn + ni * 16 + l16;
                Obase[(size_t)m * INTER + c] = f2b(d);
            }
}

// ---------------- GEMM2: out[e,m,h] = down_in @ dequant(W2)^T ----------------
__global__ __launch_bounds__(256, 2) void gemm2_kernel(
        const unsigned short* __restrict__ down_in, // [E, MPE, INTER] bf16
        const float* __restrict__ w2,               // [E, HIDDEN, INTER]
        const float* __restrict__ s2,               // [E, 16, 11]
        float* __restrict__ out)                    // [E*MPE, HIDDEN]
{
    __shared__ unsigned short sA[128 * LDP];
    __shared__ unsigned short sW[128 * LDP];

    const int nx = blockIdx.x;   // 0..15  (HIDDEN/128)
    const int my = blockIdx.y;   // 0..7
    const int e  = blockIdx.z;   // 0..7
    const int t  = threadIdx.x;
    const int lane = t & 63;
    const int wave = t >> 6;
    const int wm   = (wave >> 1) * 64;
    const int wn   = (wave & 1) * 64;
    const int l16  = lane & 15;
    const int quad = lane >> 4;

    const unsigned short* Abase = down_in + ((size_t)e * MPE + (size_t)my * 128) * INTER;
    const float* Wbase = w2 + ((size_t)e * HIDDEN + (size_t)nx * 128) * INTER;

    f32x4 acc[4][4];
    #pragma unroll
    for (int i = 0; i < 4; ++i)
        #pragma unroll
        for (int j = 0; j < 4; ++j)
            acc[i][j] = {0.f, 0.f, 0.f, 0.f};

    for (int kt = 0; kt < INTER / BK; ++kt) {
        const int k0 = kt * BK;
        const float sc = s2[(e * 16 + nx) * 11 + (k0 >> 7)];

        __syncthreads();
        // stage A (bf16 passthrough, 128 x 64)
        #pragma unroll
        for (int i = 0; i < 4; ++i) {
            int idx = i * 256 + t;
            int r = idx >> 3, c8 = idx & 7;
            uint4 v = *(const uint4*)(Abase + (size_t)r * INTER + k0 + c8 * 8);
            *(uint4*)&sA[r * LDP + c8 * 8] = v;
        }
        // stage W2 (dequant folded, f32 -> bf16)
        #pragma unroll
        for (int i = 0; i < 8; ++i) {
            int idx = i * 256 + t;
            int r = idx >> 4, c4 = idx & 15;
            float4 v = *(const float4*)(Wbase + (size_t)r * INTER + k0 + c4 * 4);
            ushort4 p = { f2b(v.x * sc), f2b(v.y * sc), f2b(v.z * sc), f2b(v.w * sc) };
            *(ushort4*)&sW[r * LDP + c4 * 4] = p;
        }
        __syncthreads();

        #pragma unroll
        for (int kk = 0; kk < BK; kk += 32) {
            bf16x8 af[4], wf[4];
            #pragma unroll
            for (int i = 0; i < 4; ++i) {
                af[i] = *(const bf16x8*)&sA[(wm + i * 16 + l16) * LDP + kk + quad * 8];
                wf[i] = *(const bf16x8*)&sW[(wn + i * 16 + l16) * LDP + kk + quad * 8];
            }
            #pragma unroll
            for (int mi = 0; mi < 4; ++mi)
                #pragma unroll
                for (int ni = 0; ni < 4; ++ni)
                    acc[mi][ni] = __builtin_amdgcn_mfma_f32_16x16x32_bf16(af[mi], wf[ni], acc[mi][ni], 0, 0, 0);
        }
    }

    float* Obase = out + ((size_t)e * MPE + (size_t)my * 128) * HIDDEN + (size_t)nx * 128;
    #pragma unroll
    for (int mi = 0; mi < 4; ++mi)
        #pragma unroll
        for (int ni = 0; ni < 4; ++ni)
            #pragma unroll
            for (int r = 0; r < 4; ++r) {
                int m = wm + mi * 16 + quad * 4 + r;
                int c = wn + ni * 16 + l16;
                Obase[(size_t)m * HIDDEN + c] = acc[mi][ni][r];
            }
}

extern "C" void kernel_launch(void* const* d_in, const int* in_sizes, int n_in,
                              void* d_out, int out_size, void* d_ws, size_t ws_size,
                              hipStream_t stream) {
    const float* hidden = (const float*)d_in[0];
    // d_in[1] = tokens_per_expert: constant 1024 each (reference ignores it; m_per_e = M//E)
    const float* w1 = (const float*)d_in[2];
    const float* s1 = (const float*)d_in[3];
    const float* w2 = (const float*)d_in[4];
    const float* s2 = (const float*)d_in[5];

    unsigned short* down_in = (unsigned short*)d_ws;  // needs 8*1024*1408*2 = 23.1 MB
    float* out = (float*)d_out;

    dim3 blk(256);
    gemm1_kernel<<<dim3(INTER / 128, MPE / 128, E_LOCAL), blk, 0, stream>>>(hidden, w1, s1, down_in);
    gemm2_kernel<<<dim3(HIDDEN / 128, MPE / 128, E_LOCAL), blk, 0, stream>>>(down_in, w2, s2, out);
}

// Round 2
// 598.220 us; speedup vs baseline: 1.9700x; 1.9700x over previous
//
#include <hip/hip_runtime.h>
#include <hip/hip_bf16.h>
#include <cstdint>

#define E_LOCAL 8
#define HIDDEN  2048
#define INTER   1408
#define MPE     1024      // tokens per expert (8192/8)
#define BK      64
#define LDP     72        // fallback-path padded LDS stride

typedef __attribute__((ext_vector_type(8))) __bf16 bf16x8;
typedef __attribute__((ext_vector_type(4))) float  f32x4;
typedef __attribute__((ext_vector_type(8))) unsigned short u16x8;

// round-to-nearest-even f32 -> bf16 bits (finite inputs)
__device__ __forceinline__ unsigned short f2b(float f) {
    unsigned int u = __float_as_uint(f);
    unsigned int r = (u + 0x7fffu + ((u >> 16) & 1u)) >> 16;
    return (unsigned short)r;
}

// async global->LDS, 16B per lane. LDS dest = wave-uniform base + lane*16.
__device__ __forceinline__ void async16(const unsigned short* g, unsigned short* l) {
    __builtin_amdgcn_global_load_lds(
        (const __attribute__((address_space(1))) unsigned int*)g,
        (__attribute__((address_space(3))) unsigned int*)l, 16, 0, 0);
}

// ---------------- one-time dequant+convert: f32 [E,N,K] * s[E,N/128,K/128] -> bf16 ----------------
__global__ __launch_bounds__(256) void convert_kernel(
        const float* __restrict__ src, const float* __restrict__ scale,
        unsigned short* __restrict__ dst, int N, int K, int K8, int NB, int KBl)
{
    const int e = blockIdx.y;
    unsigned int idx = blockIdx.x * 256u + threadIdx.x;
    unsigned int r = idx / (unsigned int)K8;
    unsigned int c = idx - r * (unsigned int)K8;
    size_t base = ((size_t)e * N + r) * K + (size_t)c * 8;
    float4 v0 = *(const float4*)(src + base);
    float4 v1 = *(const float4*)(src + base + 4);
    float s = 1.0f;
    if (scale) s = scale[((size_t)e * NB + (r >> 7)) * KBl + (c >> 4)];
    u16x8 o;
    o[0] = f2b(v0.x * s); o[1] = f2b(v0.y * s); o[2] = f2b(v0.z * s); o[3] = f2b(v0.w * s);
    o[4] = f2b(v1.x * s); o[5] = f2b(v1.y * s); o[6] = f2b(v1.z * s); o[7] = f2b(v1.w * s);
    *(u16x8*)(dst + base) = o;
}

// ---------------- GEMM1 (bf16, m97 structure): down_in = silu(A@Wg^T) * (A@Wu^T) ----------------
// LDS tiles 128x64 bf16, unpadded (global_load_lds requires lane-contiguous layout).
// XOR swizzle: stored chunk = global chunk ^ (row & 7)  => ds_read_b128 frags are 2-way aliased only.
__global__ __launch_bounds__(256, 2) void gemm1_bf16(
        const unsigned short* __restrict__ bh,    // [8192, HIDDEN] bf16
        const unsigned short* __restrict__ bw1,   // [E, 2*INTER, HIDDEN] bf16 (dequant folded)
        unsigned short* __restrict__ down_in)     // [E, MPE, INTER] bf16
{
    __shared__ alignas(16) unsigned short sA[128 * 64];
    __shared__ alignas(16) unsigned short sG[128 * 64];
    __shared__ alignas(16) unsigned short sU[128 * 64];

    const int nx = blockIdx.x;   // 0..10
    const int my = blockIdx.y;   // 0..7
    const int e  = blockIdx.z;   // 0..7
    const int t  = threadIdx.x;
    const int lane = t & 63;
    const int wave = t >> 6;
    const int wm   = (wave >> 1) * 64;
    const int wn   = (wave & 1) * 64;
    const int l16  = lane & 15;
    const int quad = lane >> 4;
    const int xq   = l16 & 7;

    const unsigned short* Abase = bh  + ((size_t)e * MPE + (size_t)my * 128) * HIDDEN;
    const unsigned short* Gbase = bw1 + ((size_t)e * (2 * INTER) + (size_t)nx * 128) * HIDDEN;
    const unsigned short* Ubase = Gbase + (size_t)INTER * HIDDEN;

    // staging: call j covers LDS slots (wave*4+j)*64 + lane; slot s -> (r=s>>3, cs=s&7); cg = cs ^ (r&7)
    const int lr  = lane >> 3;
    const int c8g = (lane & 7) ^ (lr & 7);
    const size_t lgoff = (size_t)(wave * 32 + lr) * HIDDEN + (size_t)c8g * 8; // elements, j=0
    const int ldsbase = wave * 2048; // elements; +j*512

    f32x4 accg[4][4], accu[4][4];
    #pragma unroll
    for (int i = 0; i < 4; ++i)
        #pragma unroll
        for (int j = 0; j < 4; ++j) { accg[i][j] = {0,0,0,0}; accu[i][j] = {0,0,0,0}; }

    for (int kt = 0; kt < HIDDEN / BK; ++kt) {
        const int k0 = kt * BK;
        __syncthreads();
        #pragma unroll
        for (int j = 0; j < 4; ++j) {
            const size_t go = lgoff + (size_t)j * 8 * HIDDEN + k0;
            const int lo = ldsbase + j * 512;
            async16(Abase + go, &sA[lo]);
            async16(Gbase + go, &sG[lo]);
            async16(Ubase + go, &sU[lo]);
        }
        __syncthreads(); // compiler drains vmcnt(0) before s_barrier

        #pragma unroll
        for (int kk = 0; kk < 2; ++kk) {
            bf16x8 af[4], gf[4], uf[4];
            const int cb = ((kk * 4 + quad) ^ xq) * 8;
            #pragma unroll
            for (int i = 0; i < 4; ++i) {
                af[i] = *(const bf16x8*)&sA[(wm + i * 16 + l16) * 64 + cb];
                gf[i] = *(const bf16x8*)&sG[(wn + i * 16 + l16) * 64 + cb];
                uf[i] = *(const bf16x8*)&sU[(wn + i * 16 + l16) * 64 + cb];
            }
            #pragma unroll
            for (int mi = 0; mi < 4; ++mi)
                #pragma unroll
                for (int ni = 0; ni < 4; ++ni) {
                    accg[mi][ni] = __builtin_amdgcn_mfma_f32_16x16x32_bf16(af[mi], gf[ni], accg[mi][ni], 0, 0, 0);
                    accu[mi][ni] = __builtin_amdgcn_mfma_f32_16x16x32_bf16(af[mi], uf[ni], accu[mi][ni], 0, 0, 0);
                }
        }
    }

    unsigned short* Obase = down_in + ((size_t)e * MPE + (size_t)my * 128) * INTER + (size_t)nx * 128;
    #pragma unroll
    for (int mi = 0; mi < 4; ++mi)
        #pragma unroll
        for (int ni = 0; ni < 4; ++ni)
            #pragma unroll
            for (int r = 0; r < 4; ++r) {
                float g = accg[mi][ni][r];
                float u = accu[mi][ni][r];
                float d = g / (1.f + __expf(-g)) * u;
                int m = wm + mi * 16 + quad * 4 + r;
                int c = wn + ni * 16 + l16;
                Obase[(size_t)m * INTER + c] = f2b(d);
            }
}

// ---------------- GEMM2 (bf16, m97 structure): out = down_in @ W2^T ----------------
__global__ __launch_bounds__(256, 2) void gemm2_bf16(
        const unsigned short* __restrict__ down_in, // [E, MPE, INTER] bf16
        const unsigned short* __restrict__ bw2,     // [E, HIDDEN, INTER] bf16 (dequant folded)
        float* __restrict__ out)                    // [E*MPE, HIDDEN]
{
    __shared__ alignas(16) unsigned short sA[128 * 64];
    __shared__ alignas(16) unsigned short sW[128 * 64];

    const int nx = blockIdx.x;   // 0..15
    const int my = blockIdx.y;   // 0..7
    const int e  = blockIdx.z;   // 0..7
    const int t  = threadIdx.x;
    const int lane = t & 63;
    const int wave = t >> 6;
    const int wm   = (wave >> 1) * 64;
    const int wn   = (wave & 1) * 64;
    const int l16  = lane & 15;
    const int quad = lane >> 4;
    const int xq   = l16 & 7;

    const unsigned short* Abase = down_in + ((size_t)e * MPE + (size_t)my * 128) * INTER;
    const unsigned short* Wbase = bw2 + ((size_t)e * HIDDEN + (size_t)nx * 128) * INTER;

    const int lr  = lane >> 3;
    const int c8g = (lane & 7) ^ (lr & 7);
    const size_t lgoff = (size_t)(wave * 32 + lr) * INTER + (size_t)c8g * 8;
    const int ldsbase = wave * 2048;

    f32x4 acc[4][4];
    #pragma unroll
    for (int i = 0; i < 4; ++i)
        #pragma unroll
        for (int j = 0; j < 4; ++j) acc[i][j] = {0,0,0,0};

    for (int kt = 0; kt < INTER / BK; ++kt) {
        const int k0 = kt * BK;
        __syncthreads();
        #pragma unroll
        for (int j = 0; j < 4; ++j) {
            const size_t go = lgoff + (size_t)j * 8 * INTER + k0;
            const int lo = ldsbase + j * 512;
            async16(Abase + go, &sA[lo]);
            async16(Wbase + go, &sW[lo]);
        }
        __syncthreads();

        #pragma unroll
        for (int kk = 0; kk < 2; ++kk) {
            bf16x8 af[4], wf[4];
            const int cb = ((kk * 4 + quad) ^ xq) * 8;
            #pragma unroll
            for (int i = 0; i < 4; ++i) {
                af[i] = *(const bf16x8*)&sA[(wm + i * 16 + l16) * 64 + cb];
                wf[i] = *(const bf16x8*)&sW[(wn + i * 16 + l16) * 64 + cb];
            }
            #pragma unroll
            for (int mi = 0; mi < 4; ++mi)
                #pragma unroll
                for (int ni = 0; ni < 4; ++ni)
                    acc[mi][ni] = __builtin_amdgcn_mfma_f32_16x16x32_bf16(af[mi], wf[ni], acc[mi][ni], 0, 0, 0);
        }
    }

    float* Obase = out + ((size_t)e * MPE + (size_t)my * 128) * HIDDEN + (size_t)nx * 128;
    #pragma unroll
    for (int mi = 0; mi < 4; ++mi)
        #pragma unroll
        for (int ni = 0; ni < 4; ++ni)
            #pragma unroll
            for (int r = 0; r < 4; ++r) {
                int m = wm + mi * 16 + quad * 4 + r;
                int c = wn + ni * 16 + l16;
                Obase[(size_t)m * HIDDEN + c] = acc[mi][ni][r];
            }
}

// =================== fallback path (round-1 f32 kernels, used only if ws too small) ===================
__global__ __launch_bounds__(256, 2) void gemm1_f32(
        const float* __restrict__ hidden, const float* __restrict__ w1,
        const float* __restrict__ s1, unsigned short* __restrict__ down_in)
{
    __shared__ unsigned short sA[128 * LDP];
    __shared__ unsigned short sG[128 * LDP];
    __shared__ unsigned short sU[128 * LDP];
    const int nx = blockIdx.x, my = blockIdx.y, e = blockIdx.z;
    const int t = threadIdx.x, lane = t & 63, wave = t >> 6;
    const int wm = (wave >> 1) * 64, wn = (wave & 1) * 64;
    const int l16 = lane & 15, quad = lane >> 4;
    const float* Abase = hidden + ((size_t)e * MPE + (size_t)my * 128) * HIDDEN;
    const float* Gbase = w1 + ((size_t)e * (2 * INTER) + (size_t)nx * 128) * HIDDEN;
    const float* Ubase = w1 + ((size_t)e * (2 * INTER) + INTER + (size_t)nx * 128) * HIDDEN;
    f32x4 accg[4][4], accu[4][4];
    #pragma unroll
    for (int i = 0; i < 4; ++i)
        #pragma unroll
        for (int j = 0; j < 4; ++j) { accg[i][j] = {0,0,0,0}; accu[i][j] = {0,0,0,0}; }
    for (int kt = 0; kt < HIDDEN / BK; ++kt) {
        const int k0 = kt * BK;
        const int kb = k0 >> 7;
        const float sg = s1[(e * 22 + nx) * 16 + kb];
        const float su = s1[(e * 22 + 11 + nx) * 16 + kb];
        __syncthreads();
        #pragma unroll
        for (int i = 0; i < 8; ++i) {
            int idx = i * 256 + t; int r = idx >> 4, c4 = idx & 15;
            float4 v = *(const float4*)(Abase + (size_t)r * HIDDEN + k0 + c4 * 4);
            ushort4 p = { f2b(v.x), f2b(v.y), f2b(v.z), f2b(v.w) };
            *(ushort4*)&sA[r * LDP + c4 * 4] = p;
        }
        #pragma unroll
        for (int i = 0; i < 8; ++i) {
            int idx = i * 256 + t; int r = idx >> 4, c4 = idx & 15;
            float4 v = *(const float4*)(Gbase + (size_t)r * HIDDEN + k0 + c4 * 4);
            ushort4 p = { f2b(v.x * sg), f2b(v.y * sg), f2b(v.z * sg), f2b(v.w * sg) };
            *(ushort4*)&sG[r * LDP + c4 * 4] = p;
        }
        #pragma unroll
        for (int i = 0; i < 8; ++i) {
            int idx = i * 256 + t; int r = idx >> 4, c4 = idx & 15;
            float4 v = *(const float4*)(Ubase + (size_t)r * HIDDEN + k0 + c4 * 4);
            ushort4 p = { f2b(v.x * su), f2b(v.y * su), f2b(v.z * su), f2b(v.w * su) };
            *(ushort4*)&sU[r * LDP + c4 * 4] = p;
        }
        __syncthreads();
        #pragma unroll
        for (int kk = 0; kk < BK; kk += 32) {
            bf16x8 af[4], gf[4], uf[4];
            #pragma unroll
            for (int i = 0; i < 4; ++i) {
                af[i] = *(const bf16x8*)&sA[(wm + i * 16 + l16) * LDP + kk + quad * 8];
                gf[i] = *(const bf16x8*)&sG[(wn + i * 16 + l16) * LDP + kk + quad * 8];
                uf[i] = *(const bf16x8*)&sU[(wn + i * 16 + l16) * LDP + kk + quad * 8];
            }
            #pragma unroll
            for (int mi = 0; mi < 4; ++mi)
                #pragma unroll
                for (int ni = 0; ni < 4; ++ni) {
                    accg[mi][ni] = __builtin_amdgcn_mfma_f32_16x16x32_bf16(af[mi], gf[ni], accg[mi][ni], 0, 0, 0);
                    accu[mi][ni] = __builtin_amdgcn_mfma_f32_16x16x32_bf16(af[mi], uf[ni], accu[mi][ni], 0, 0, 0);
                }
        }
    }
    unsigned short* Obase = down_in + ((size_t)e * MPE + (size_t)my * 128) * INTER + (size_t)nx * 128;
    #pragma unroll
    for (int mi = 0; mi < 4; ++mi)
        #pragma unroll
        for (int ni = 0; ni < 4; ++ni)
            #pragma unroll
            for (int r = 0; r < 4; ++r) {
                float g = accg[mi][ni][r], u = accu[mi][ni][r];
                float d = g / (1.f + __expf(-g)) * u;
                int m = wm + mi * 16 + quad * 4 + r, c = wn + ni * 16 + l16;
                Obase[(size_t)m * INTER + c] = f2b(d);
            }
}

__global__ __launch_bounds__(256, 2) void gemm2_f32(
        const unsigned short* __restrict__ down_in, const float* __restrict__ w2,
        const float* __restrict__ s2, float* __restrict__ out)
{
    __shared__ unsigned short sA[128 * LDP];
    __shared__ unsigned short sW[128 * LDP];
    const int nx = blockIdx.x, my = blockIdx.y, e = blockIdx.z;
    const int t = threadIdx.x, lane = t & 63, wave = t >> 6;
    const int wm = (wave >> 1) * 64, wn = (wave & 1) * 64;
    const int l16 = lane & 15, quad = lane >> 4;
    const unsigned short* Abase = down_in + ((size_t)e * MPE + (size_t)my * 128) * INTER;
    const float* Wbase = w2 + ((size_t)e * HIDDEN + (size_t)nx * 128) * INTER;
    f32x4 acc[4][4];
    #pragma unroll
    for (int i = 0; i < 4; ++i)
        #pragma unroll
        for (int j = 0; j < 4; ++j) acc[i][j] = {0,0,0,0};
    for (int kt = 0; kt < INTER / BK; ++kt) {
        const int k0 = kt * BK;
        const float sc = s2[(e * 16 + nx) * 11 + (k0 >> 7)];
        __syncthreads();
        #pragma unroll
        for (int i = 0; i < 4; ++i) {
            int idx = i * 256 + t; int r = idx >> 3, c8 = idx & 7;
            uint4 v = *(const uint4*)(Abase + (size_t)r * INTER + k0 + c8 * 8);
            *(uint4*)&sA[r * LDP + c8 * 8] = v;
        }
        #pragma unroll
        for (int i = 0; i < 8; ++i) {
            int idx = i * 256 + t; int r = idx >> 4, c4 = idx & 15;
            float4 v = *(const float4*)(Wbase + (size_t)r * INTER + k0 + c4 * 4);
            ushort4 p = { f2b(v.x * sc), f2b(v.y * sc), f2b(v.z * sc), f2b(v.w * sc) };
            *(ushort4*)&sW[r * LDP + c4 * 4] = p;
        }
        __syncthreads();
        #pragma unroll
        for (int kk = 0; kk < BK; kk += 32) {
            bf16x8 af[4], wf[4];
            #pragma unroll
            for (int i = 0; i < 4; ++i) {
                af[i] = *(const bf16x8*)&sA[(wm + i * 16 + l16) * LDP + kk + quad * 8];
                wf[i] = *(const bf16x8*)&sW[(wn + i * 16 + l16) * LDP + kk + quad * 8];
            }
            #pragma unroll
            for (int mi = 0; mi < 4; ++mi)
                #pragma unroll
                for (int ni = 0; ni < 4; ++ni)
                    acc[mi][ni] = __builtin_amdgcn_mfma_f32_16x16x32_bf16(af[mi], wf[ni], acc[mi][ni], 0, 0, 0);
        }
    }
    float* Obase = out + ((size_t)e * MPE + (size_t)my * 128) * HIDDEN + (size_t)nx * 128;
    #pragma unroll
    for (int mi = 0; mi < 4; ++mi)
        #pragma unroll
        for (int ni = 0; ni < 4; ++ni)
            #pragma unroll
            for (int r = 0; r < 4; ++r) {
                int m = wm + mi * 16 + quad * 4 + r, c = wn + ni * 16 + l16;
                Obase[(size_t)m * HIDDEN + c] = acc[mi][ni][r];
            }
}

extern "C" void kernel_launch(void* const* d_in, const int* in_sizes, int n_in,
                              void* d_out, int out_size, void* d_ws, size_t ws_size,
                              hipStream_t stream) {
    const float* hidden = (const float*)d_in[0];
    const float* w1 = (const float*)d_in[2];
    const float* s1 = (const float*)d_in[3];
    const float* w2 = (const float*)d_in[4];
    const float* s2 = (const float*)d_in[5];
    float* out = (float*)d_out;

    const size_t SZ_BH  = (size_t)8192 * HIDDEN * 2;          // 33.55 MB
    const size_t SZ_BW1 = (size_t)E_LOCAL * 2 * INTER * HIDDEN * 2; // 92.27 MB
    const size_t SZ_BW2 = (size_t)E_LOCAL * HIDDEN * INTER * 2;     // 46.14 MB
    const size_t SZ_DI  = (size_t)E_LOCAL * MPE * INTER * 2;        // 23.07 MB
    const size_t NEED = SZ_BH + SZ_BW1 + SZ_BW2 + SZ_DI;

    dim3 blk(256);
    if (ws_size >= NEED) {
        char* w = (char*)d_ws;
        unsigned short* bh      = (unsigned short*)w;            w += SZ_BH;
        unsigned short* bw1     = (unsigned short*)w;            w += SZ_BW1;
        unsigned short* bw2     = (unsigned short*)w;            w += SZ_BW2;
        unsigned short* down_in = (unsigned short*)w;

        // hidden: [8192, 2048] no scale
        convert_kernel<<<dim3(8192, 1), blk, 0, stream>>>(hidden, nullptr, bh, 8192, HIDDEN, HIDDEN / 8, 0, 0);
        // w1: [E, 2816, 2048], scale [E,22,16]
        convert_kernel<<<dim3(2816, E_LOCAL), blk, 0, stream>>>(w1, s1, bw1, 2 * INTER, HIDDEN, HIDDEN / 8, 22, 16);
        // w2: [E, 2048, 1408], scale [E,16,11]
        convert_kernel<<<dim3(1408, E_LOCAL), blk, 0, stream>>>(w2, s2, bw2, HIDDEN, INTER, INTER / 8, 16, 11);

        gemm1_bf16<<<dim3(INTER / 128, MPE / 128, E_LOCAL), blk, 0, stream>>>(bh, bw1, down_in);
        gemm2_bf16<<<dim3(HIDDEN / 128, MPE / 128, E_LOCAL), blk, 0, stream>>>(down_in, bw2, out);
    } else {
        unsigned short* down_in = (unsigned short*)d_ws;
        gemm1_f32<<<dim3(INTER / 128, MPE / 128, E_LOCAL), blk, 0, stream>>>(hidden, w1, s1, down_in);
        gemm2_f32<<<dim3(HIDDEN / 128, MPE / 128, E_LOCAL), blk, 0, stream>>>(down_in, w2, s2, out);
    }
}

// Round 3
// 588.786 us; speedup vs baseline: 2.0016x; 1.0160x over previous
//
#include <hip/hip_runtime.h>
#include <hip/hip_bf16.h>
#include <cstdint>

#define E_LOCAL 8
#define HIDDEN  2048
#define INTER   1408
#define MPE     1024      // tokens per expert (8192/8)
#define BK      64
#define LDP     72        // fallback-path padded LDS stride

typedef __attribute__((ext_vector_type(8))) __bf16 bf16x8;
typedef __attribute__((ext_vector_type(4))) float  f32x4;
typedef __attribute__((ext_vector_type(8))) unsigned short u16x8;

// round-to-nearest-even f32 -> bf16 bits (finite inputs)
__device__ __forceinline__ unsigned short f2b(float f) {
    unsigned int u = __float_as_uint(f);
    unsigned int r = (u + 0x7fffu + ((u >> 16) & 1u)) >> 16;
    return (unsigned short)r;
}

// async global->LDS, 16B per lane. LDS dest = wave-uniform base + lane*16.
__device__ __forceinline__ void async16(const unsigned short* g, unsigned short* l) {
    __builtin_amdgcn_global_load_lds(
        (const __attribute__((address_space(1))) unsigned int*)g,
        (__attribute__((address_space(3))) unsigned int*)l, 16, 0, 0);
}

// ---------------- one-time dequant+convert: f32 [E,N,K] * s[E,N/128,K/128] -> bf16 ----------------
// 16 elems per thread (64B in, 32B out). All 16 elems lie in one row and one 128-k-block.
__global__ __launch_bounds__(256) void convert_kernel(
        const float* __restrict__ src, const float* __restrict__ scale,
        unsigned short* __restrict__ dst, int N, int K, int K16, int NB, int KBl)
{
    const int e = blockIdx.y;
    unsigned int idx = blockIdx.x * 256u + threadIdx.x;   // 16-elem chunk id within expert
    unsigned int r   = idx / (unsigned int)K16;
    unsigned int c16 = idx - r * (unsigned int)K16;
    size_t base = ((size_t)e * N + r) * K + (size_t)c16 * 16;
    float4 v0 = *(const float4*)(src + base);
    float4 v1 = *(const float4*)(src + base + 4);
    float4 v2 = *(const float4*)(src + base + 8);
    float4 v3 = *(const float4*)(src + base + 12);
    float s = 1.0f;
    if (scale) s = scale[((size_t)e * NB + (r >> 7)) * KBl + (c16 >> 3)];
    u16x8 o0, o1;
    o0[0] = f2b(v0.x * s); o0[1] = f2b(v0.y * s); o0[2] = f2b(v0.z * s); o0[3] = f2b(v0.w * s);
    o0[4] = f2b(v1.x * s); o0[5] = f2b(v1.y * s); o0[6] = f2b(v1.z * s); o0[7] = f2b(v1.w * s);
    o1[0] = f2b(v2.x * s); o1[1] = f2b(v2.y * s); o1[2] = f2b(v2.z * s); o1[3] = f2b(v2.w * s);
    o1[4] = f2b(v3.x * s); o1[5] = f2b(v3.y * s); o1[6] = f2b(v3.z * s); o1[7] = f2b(v3.w * s);
    *(u16x8*)(dst + base)     = o0;
    *(u16x8*)(dst + base + 8) = o1;
}

// ---------------- GEMM1 (bf16, m97 structure): down_in = silu(A@Wg^T) * (A@Wu^T) ----------------
// grid: x = my (8 => one per XCD; same-XCD successors share the A-tile -> L2-hot),
//       y = nx (11), z = e (8). 8 consecutive blocks share one weight tile (HBM once, LLC x7).
// LDS tiles 128x64 bf16, unpadded (global_load_lds needs lane-contiguous layout).
// XOR swizzle: stored chunk = global chunk ^ (row & 7) => ds_read_b128 frags 2-way aliased only (free).
__global__ __launch_bounds__(256, 2) void gemm1_bf16(
        const unsigned short* __restrict__ bh,    // [8192, HIDDEN] bf16
        const unsigned short* __restrict__ bw1,   // [E, 2*INTER, HIDDEN] bf16 (dequant folded)
        unsigned short* __restrict__ down_in)     // [E, MPE, INTER] bf16
{
    __shared__ alignas(16) unsigned short sA[128 * 64];
    __shared__ alignas(16) unsigned short sG[128 * 64];
    __shared__ alignas(16) unsigned short sU[128 * 64];

    const int my = blockIdx.x;   // 0..7
    const int nx = blockIdx.y;   // 0..10
    const int e  = blockIdx.z;   // 0..7
    const int t  = threadIdx.x;
    const int lane = t & 63;
    const int wave = t >> 6;
    const int wm   = (wave >> 1) * 64;
    const int wn   = (wave & 1) * 64;
    const int l16  = lane & 15;
    const int quad = lane >> 4;
    const int xq   = l16 & 7;

    const unsigned short* Abase = bh  + ((size_t)e * MPE + (size_t)my * 128) * HIDDEN;
    const unsigned short* Gbase = bw1 + ((size_t)e * (2 * INTER) + (size_t)nx * 128) * HIDDEN;
    const unsigned short* Ubase = Gbase + (size_t)INTER * HIDDEN;

    // staging: call j covers LDS slots (wave*4+j)*64 + lane; slot s -> (r=s>>3, cs=s&7); cg = cs ^ (r&7)
    const int lr  = lane >> 3;
    const int c8g = (lane & 7) ^ (lr & 7);
    const size_t lgoff = (size_t)(wave * 32 + lr) * HIDDEN + (size_t)c8g * 8; // elements, j=0
    const int ldsbase = wave * 2048; // elements; +j*512

    f32x4 accg[4][4], accu[4][4];
    #pragma unroll
    for (int i = 0; i < 4; ++i)
        #pragma unroll
        for (int j = 0; j < 4; ++j) { accg[i][j] = {0,0,0,0}; accu[i][j] = {0,0,0,0}; }

    for (int kt = 0; kt < HIDDEN / BK; ++kt) {
        const int k0 = kt * BK;
        __syncthreads();
        #pragma unroll
        for (int j = 0; j < 4; ++j) {
            const size_t go = lgoff + (size_t)j * 8 * HIDDEN + k0;
            const int lo = ldsbase + j * 512;
            async16(Abase + go, &sA[lo]);
            async16(Gbase + go, &sG[lo]);
            async16(Ubase + go, &sU[lo]);
        }
        __syncthreads(); // compiler drains vmcnt(0) before s_barrier

        #pragma unroll
        for (int kk = 0; kk < 2; ++kk) {
            bf16x8 af[4], gf[4], uf[4];
            const int cb = ((kk * 4 + quad) ^ xq) * 8;
            #pragma unroll
            for (int i = 0; i < 4; ++i) {
                af[i] = *(const bf16x8*)&sA[(wm + i * 16 + l16) * 64 + cb];
                gf[i] = *(const bf16x8*)&sG[(wn + i * 16 + l16) * 64 + cb];
                uf[i] = *(const bf16x8*)&sU[(wn + i * 16 + l16) * 64 + cb];
            }
            #pragma unroll
            for (int mi = 0; mi < 4; ++mi)
                #pragma unroll
                for (int ni = 0; ni < 4; ++ni) {
                    accg[mi][ni] = __builtin_amdgcn_mfma_f32_16x16x32_bf16(af[mi], gf[ni], accg[mi][ni], 0, 0, 0);
                    accu[mi][ni] = __builtin_amdgcn_mfma_f32_16x16x32_bf16(af[mi], uf[ni], accu[mi][ni], 0, 0, 0);
                }
        }
    }

    unsigned short* Obase = down_in + ((size_t)e * MPE + (size_t)my * 128) * INTER + (size_t)nx * 128;
    #pragma unroll
    for (int mi = 0; mi < 4; ++mi)
        #pragma unroll
        for (int ni = 0; ni < 4; ++ni)
            #pragma unroll
            for (int r = 0; r < 4; ++r) {
                float g = accg[mi][ni][r];
                float u = accu[mi][ni][r];
                float d = g / (1.f + __expf(-g)) * u;
                int m = wm + mi * 16 + quad * 4 + r;
                int c = wn + ni * 16 + l16;
                Obase[(size_t)m * INTER + c] = f2b(d);
            }
}

// ---------------- GEMM2 (bf16, m97 structure): out = down_in @ W2^T ----------------
// grid: x = my (8), y = nx (16), z = e (8) -- same XCD-locality scheme as gemm1.
__global__ __launch_bounds__(256, 2) void gemm2_bf16(
        const unsigned short* __restrict__ down_in, // [E, MPE, INTER] bf16
        const unsigned short* __restrict__ bw2,     // [E, HIDDEN, INTER] bf16 (dequant folded)
        float* __restrict__ out)                    // [E*MPE, HIDDEN]
{
    __shared__ alignas(16) unsigned short sA[128 * 64];
    __shared__ alignas(16) unsigned short sW[128 * 64];

    const int my = blockIdx.x;   // 0..7
    const int nx = blockIdx.y;   // 0..15
    const int e  = blockIdx.z;   // 0..7
    const int t  = threadIdx.x;
    const int lane = t & 63;
    const int wave = t >> 6;
    const int wm   = (wave >> 1) * 64;
    const int wn   = (wave & 1) * 64;
    const int l16  = lane & 15;
    const int quad = lane >> 4;
    const int xq   = l16 & 7;

    const unsigned short* Abase = down_in + ((size_t)e * MPE + (size_t)my * 128) * INTER;
    const unsigned short* Wbase = bw2 + ((size_t)e * HIDDEN + (size_t)nx * 128) * INTER;

    const int lr  = lane >> 3;
    const int c8g = (lane & 7) ^ (lr & 7);
    const size_t lgoff = (size_t)(wave * 32 + lr) * INTER + (size_t)c8g * 8;
    const int ldsbase = wave * 2048;

    f32x4 acc[4][4];
    #pragma unroll
    for (int i = 0; i < 4; ++i)
        #pragma unroll
        for (int j = 0; j < 4; ++j) acc[i][j] = {0,0,0,0};

    for (int kt = 0; kt < INTER / BK; ++kt) {
        const int k0 = kt * BK;
        __syncthreads();
        #pragma unroll
        for (int j = 0; j < 4; ++j) {
            const size_t go = lgoff + (size_t)j * 8 * INTER + k0;
            const int lo = ldsbase + j * 512;
            async16(Abase + go, &sA[lo]);
            async16(Wbase + go, &sW[lo]);
        }
        __syncthreads();

        #pragma unroll
        for (int kk = 0; kk < 2; ++kk) {
            bf16x8 af[4], wf[4];
            const int cb = ((kk * 4 + quad) ^ xq) * 8;
            #pragma unroll
            for (int i = 0; i < 4; ++i) {
                af[i] = *(const bf16x8*)&sA[(wm + i * 16 + l16) * 64 + cb];
                wf[i] = *(const bf16x8*)&sW[(wn + i * 16 + l16) * 64 + cb];
            }
            #pragma unroll
            for (int mi = 0; mi < 4; ++mi)
                #pragma unroll
                for (int ni = 0; ni < 4; ++ni)
                    acc[mi][ni] = __builtin_amdgcn_mfma_f32_16x16x32_bf16(af[mi], wf[ni], acc[mi][ni], 0, 0, 0);
        }
    }

    float* Obase = out + ((size_t)e * MPE + (size_t)my * 128) * HIDDEN + (size_t)nx * 128;
    #pragma unroll
    for (int mi = 0; mi < 4; ++mi)
        #pragma unroll
        for (int ni = 0; ni < 4; ++ni)
            #pragma unroll
            for (int r = 0; r < 4; ++r) {
                int m = wm + mi * 16 + quad * 4 + r;
                int c = wn + ni * 16 + l16;
                Obase[(size_t)m * HIDDEN + c] = acc[mi][ni][r];
            }
}

// =================== fallback path (round-1 f32 kernels, used only if ws too small) ===================
__global__ __launch_bounds__(256, 2) void gemm1_f32(
        const float* __restrict__ hidden, const float* __restrict__ w1,
        const float* __restrict__ s1, unsigned short* __restrict__ down_in)
{
    __shared__ unsigned short sA[128 * LDP];
    __shared__ unsigned short sG[128 * LDP];
    __shared__ unsigned short sU[128 * LDP];
    const int nx = blockIdx.x, my = blockIdx.y, e = blockIdx.z;
    const int t = threadIdx.x, lane = t & 63, wave = t >> 6;
    const int wm = (wave >> 1) * 64, wn = (wave & 1) * 64;
    const int l16 = lane & 15, quad = lane >> 4;
    const float* Abase = hidden + ((size_t)e * MPE + (size_t)my * 128) * HIDDEN;
    const float* Gbase = w1 + ((size_t)e * (2 * INTER) + (size_t)nx * 128) * HIDDEN;
    const float* Ubase = w1 + ((size_t)e * (2 * INTER) + INTER + (size_t)nx * 128) * HIDDEN;
    f32x4 accg[4][4], accu[4][4];
    #pragma unroll
    for (int i = 0; i < 4; ++i)
        #pragma unroll
        for (int j = 0; j < 4; ++j) { accg[i][j] = {0,0,0,0}; accu[i][j] = {0,0,0,0}; }
    for (int kt = 0; kt < HIDDEN / BK; ++kt) {
        const int k0 = kt * BK;
        const int kb = k0 >> 7;
        const float sg = s1[(e * 22 + nx) * 16 + kb];
        const float su = s1[(e * 22 + 11 + nx) * 16 + kb];
        __syncthreads();
        #pragma unroll
        for (int i = 0; i < 8; ++i) {
            int idx = i * 256 + t; int r = idx >> 4, c4 = idx & 15;
            float4 v = *(const float4*)(Abase + (size_t)r * HIDDEN + k0 + c4 * 4);
            ushort4 p = { f2b(v.x), f2b(v.y), f2b(v.z), f2b(v.w) };
            *(ushort4*)&sA[r * LDP + c4 * 4] = p;
        }
        #pragma unroll
        for (int i = 0; i < 8; ++i) {
            int idx = i * 256 + t; int r = idx >> 4, c4 = idx & 15;
            float4 v = *(const float4*)(Gbase + (size_t)r * HIDDEN + k0 + c4 * 4);
            ushort4 p = { f2b(v.x * sg), f2b(v.y * sg), f2b(v.z * sg), f2b(v.w * sg) };
            *(ushort4*)&sG[r * LDP + c4 * 4] = p;
        }
        #pragma unroll
        for (int i = 0; i < 8; ++i) {
            int idx = i * 256 + t; int r = idx >> 4, c4 = idx & 15;
            float4 v = *(const float4*)(Ubase + (size_t)r * HIDDEN + k0 + c4 * 4);
            ushort4 p = { f2b(v.x * su), f2b(v.y * su), f2b(v.z * su), f2b(v.w * su) };
            *(ushort4*)&sU[r * LDP + c4 * 4] = p;
        }
        __syncthreads();
        #pragma unroll
        for (int kk = 0; kk < BK; kk += 32) {
            bf16x8 af[4], gf[4], uf[4];
            #pragma unroll
            for (int i = 0; i < 4; ++i) {
                af[i] = *(const bf16x8*)&sA[(wm + i * 16 + l16) * LDP + kk + quad * 8];
                gf[i] = *(const bf16x8*)&sG[(wn + i * 16 + l16) * LDP + kk + quad * 8];
                uf[i] = *(const bf16x8*)&sU[(wn + i * 16 + l16) * LDP + kk + quad * 8];
            }
            #pragma unroll
            for (int mi = 0; mi < 4; ++mi)
                #pragma unroll
                for (int ni = 0; ni < 4; ++ni) {
                    accg[mi][ni] = __builtin_amdgcn_mfma_f32_16x16x32_bf16(af[mi], gf[ni], accg[mi][ni], 0, 0, 0);
                    accu[mi][ni] = __builtin_amdgcn_mfma_f32_16x16x32_bf16(af[mi], uf[ni], accu[mi][ni], 0, 0, 0);
                }
        }
    }
    unsigned short* Obase = down_in + ((size_t)e * MPE + (size_t)my * 128) * INTER + (size_t)nx * 128;
    #pragma unroll
    for (int mi = 0; mi < 4; ++mi)
        #pragma unroll
        for (int ni = 0; ni < 4; ++ni)
            #pragma unroll
            for (int r = 0; r < 4; ++r) {
                float g = accg[mi][ni][r], u = accu[mi][ni][r];
                float d = g / (1.f + __expf(-g)) * u;
                int m = wm + mi * 16 + quad * 4 + r, c = wn + ni * 16 + l16;
                Obase[(size_t)m * INTER + c] = f2b(d);
            }
}

__global__ __launch_bounds__(256, 2) void gemm2_f32(
        const unsigned short* __restrict__ down_in, const float* __restrict__ w2,
        const float* __restrict__ s2, float* __restrict__ out)
{
    __shared__ unsigned short sA[128 * LDP];
    __shared__ unsigned short sW[128 * LDP];
    const int nx = blockIdx.x, my = blockIdx.y, e = blockIdx.z;
    const int t = threadIdx.x, lane = t & 63, wave = t >> 6;
    const int wm = (wave >> 1) * 64, wn = (wave & 1) * 64;
    const int l16 = lane & 15, quad = lane >> 4;
    const unsigned short* Abase = down_in + ((size_t)e * MPE + (size_t)my * 128) * INTER;
    const float* Wbase = w2 + ((size_t)e * HIDDEN + (size_t)nx * 128) * INTER;
    f32x4 acc[4][4];
    #pragma unroll
    for (int i = 0; i < 4; ++i)
        #pragma unroll
        for (int j = 0; j < 4; ++j) acc[i][j] = {0,0,0,0};
    for (int kt = 0; kt < INTER / BK; ++kt) {
        const int k0 = kt * BK;
        const float sc = s2[(e * 16 + nx) * 11 + (k0 >> 7)];
        __syncthreads();
        #pragma unroll
        for (int i = 0; i < 4; ++i) {
            int idx = i * 256 + t; int r = idx >> 3, c8 = idx & 7;
            uint4 v = *(const uint4*)(Abase + (size_t)r * INTER + k0 + c8 * 8);
            *(uint4*)&sA[r * LDP + c8 * 8] = v;
        }
        #pragma unroll
        for (int i = 0; i < 8; ++i) {
            int idx = i * 256 + t; int r = idx >> 4, c4 = idx & 15;
            float4 v = *(const float4*)(Wbase + (size_t)r * INTER + k0 + c4 * 4);
            ushort4 p = { f2b(v.x * sc), f2b(v.y * sc), f2b(v.z * sc), f2b(v.w * sc) };
            *(ushort4*)&sW[r * LDP + c4 * 4] = p;
        }
        __syncthreads();
        #pragma unroll
        for (int kk = 0; kk < BK; kk += 32) {
            bf16x8 af[4], wf[4];
            #pragma unroll
            for (int i = 0; i < 4; ++i) {
                af[i] = *(const bf16x8*)&sA[(wm + i * 16 + l16) * LDP + kk + quad * 8];
                wf[i] = *(const bf16x8*)&sW[(wn + i * 16 + l16) * LDP + kk + quad * 8];
            }
            #pragma unroll
            for (int mi = 0; mi < 4; ++mi)
                #pragma unroll
                for (int ni = 0; ni < 4; ++ni)
                    acc[mi][ni] = __builtin_amdgcn_mfma_f32_16x16x32_bf16(af[mi], wf[ni], acc[mi][ni], 0, 0, 0);
        }
    }
    float* Obase = out + ((size_t)e * MPE + (size_t)my * 128) * HIDDEN + (size_t)nx * 128;
    #pragma unroll
    for (int mi = 0; mi < 4; ++mi)
        #pragma unroll
        for (int ni = 0; ni < 4; ++ni)
            #pragma unroll
            for (int r = 0; r < 4; ++r) {
                int m = wm + mi * 16 + quad * 4 + r, c = wn + ni * 16 + l16;
                Obase[(size_t)m * HIDDEN + c] = acc[mi][ni][r];
            }
}

extern "C" void kernel_launch(void* const* d_in, const int* in_sizes, int n_in,
                              void* d_out, int out_size, void* d_ws, size_t ws_size,
                              hipStream_t stream) {
    const float* hidden = (const float*)d_in[0];
    const float* w1 = (const float*)d_in[2];
    const float* s1 = (const float*)d_in[3];
    const float* w2 = (const float*)d_in[4];
    const float* s2 = (const float*)d_in[5];
    float* out = (float*)d_out;

    const size_t SZ_BH  = (size_t)8192 * HIDDEN * 2;                // 33.55 MB
    const size_t SZ_BW1 = (size_t)E_LOCAL * 2 * INTER * HIDDEN * 2; // 92.27 MB
    const size_t SZ_BW2 = (size_t)E_LOCAL * HIDDEN * INTER * 2;     // 46.14 MB
    const size_t SZ_DI  = (size_t)E_LOCAL * MPE * INTER * 2;        // 23.07 MB
    const size_t NEED = SZ_BH + SZ_BW1 + SZ_BW2 + SZ_DI;

    dim3 blk(256);
    if (ws_size >= NEED) {
        char* w = (char*)d_ws;
        unsigned short* bh      = (unsigned short*)w;            w += SZ_BH;
        unsigned short* bw1     = (unsigned short*)w;            w += SZ_BW1;
        unsigned short* bw2     = (unsigned short*)w;            w += SZ_BW2;
        unsigned short* down_in = (unsigned short*)w;

        // hidden: [8192, 2048], no scale. 8192*2048/16/256 = 4096 blocks
        convert_kernel<<<dim3(4096, 1), blk, 0, stream>>>(hidden, nullptr, bh, 8192, HIDDEN, HIDDEN / 16, 0, 0);
        // w1: [E, 2816, 2048], scale [E,22,16]. 2816*2048/16/256 = 1408 blocks/expert
        convert_kernel<<<dim3(1408, E_LOCAL), blk, 0, stream>>>(w1, s1, bw1, 2 * INTER, HIDDEN, HIDDEN / 16, 22, 16);
        // w2: [E, 2048, 1408], scale [E,16,11]. 2048*1408/16/256 = 704 blocks/expert
        convert_kernel<<<dim3(704, E_LOCAL), blk, 0, stream>>>(w2, s2, bw2, HIDDEN, INTER, INTER / 16, 16, 11);

        gemm1_bf16<<<dim3(MPE / 128, INTER / 128, E_LOCAL), blk, 0, stream>>>(bh, bw1, down_in);
        gemm2_bf16<<<dim3(MPE / 128, HIDDEN / 128, E_LOCAL), blk, 0, stream>>>(down_in, bw2, out);
    } else {
        unsigned short* down_in = (unsigned short*)d_ws;
        gemm1_f32<<<dim3(INTER / 128, MPE / 128, E_LOCAL), blk, 0, stream>>>(hidden, w1, s1, down_in);
        gemm2_f32<<<dim3(HIDDEN / 128, MPE / 128, E_LOCAL), blk, 0, stream>>>(down_in, w2, s2, out);
    }
}